// Round 2
// baseline (508.848 us; speedup 1.0000x reference)
//
#include <hip/hip_runtime.h>
#include <hip/hip_bf16.h>
#include <math.h>

#define NB   1024
#define NS   60
#define ND   256
#define NH   1024
#define NE   8
#define NCAP 256
#define NTOK (NCAP*NS)      // 15360 tokens per expert
#define BM   64
#define NBLK (NTOK/BM)      // 240 row-tiles per expert
#define A_PAD 264           // 256+8 shorts; row stride 528B = 16B-aligned, 2-way conflicts only
#define P_PAD 132           // 132 shorts = 264B rows: quads land on disjoint bank octets (write conflict-free)

typedef __attribute__((ext_vector_type(8))) short  short8;
typedef __attribute__((ext_vector_type(4))) short  s4v;
typedef __attribute__((ext_vector_type(4))) float  floatx4;

__device__ __forceinline__ unsigned short f2bf(float f) {
    union { float f; unsigned u; } cv; cv.f = f;
    unsigned u = cv.u;
    u += 0x7FFFu + ((u >> 16) & 1u);   // round-to-nearest-even
    return (unsigned short)(u >> 16);
}
__device__ __forceinline__ float bf2f(unsigned short h) {
    union { unsigned u; float f; } c; c.u = ((unsigned)h) << 16; return c.f;
}

// ---------------- pack W1 [E,256,1024] fp32 -> MFMA B-fragment order bf16 (coalesced reads)
// fragment f=(e*64+hnt)*8+kt ; element lane*8+j = W1[e][kt*32+(lane>>4)*8+j][hnt*16+(lane&15)]
__global__ void k_pack_w1(const float* __restrict__ W1, unsigned short* __restrict__ W1b) {
    int idx = blockIdx.x * 256 + threadIdx.x;       // 524288
    int n4 = idx & 255;
    int k  = (idx >> 8) & 255;
    int e  = idx >> 16;
    int n  = n4 * 4;
    float4 w = *(const float4*)(W1 + ((size_t)(e * 256 + k)) * 1024 + n);
    int f = (e * 64 + (n >> 4)) * 8 + (k >> 5);
    int L = ((k >> 3) & 3) * 16 + (n & 15);
    int j = k & 7;
    unsigned short* dst = W1b + (size_t)f * 512 + L * 8 + j;
    dst[0]  = f2bf(w.x);
    dst[8]  = f2bf(w.y);
    dst[16] = f2bf(w.z);
    dst[24] = f2bf(w.w);
}

// ---------------- pack W2 [E,1024,256] fp32 -> fragment order bf16 (coalesced reads)
__global__ void k_pack_w2(const float* __restrict__ W2, unsigned short* __restrict__ W2b) {
    int idx = blockIdx.x * 256 + threadIdx.x;       // 524288
    int d4 = idx & 63;
    int h  = (idx >> 6) & 1023;
    int e  = idx >> 16;
    int d  = d4 * 4;
    float4 w = *(const float4*)(W2 + ((size_t)(e * 1024 + h)) * 256 + d);
    int f = (e * 16 + (d >> 4)) * 32 + (h >> 5);
    int L = ((h >> 3) & 3) * 16 + (d & 15);
    int j = h & 7;
    unsigned short* dst = W2b + (size_t)f * 512 + L * 8 + j;
    dst[0]  = f2bf(w.x);
    dst[8]  = f2bf(w.y);
    dst[16] = f2bf(w.z);
    dst[24] = f2bf(w.w);
}

// ---------------- routing split-K GEMM fused with x->bf16 prep.
// grid: 128 row-groups x 8 k-splits. block: 8 teams x 32 threads.
// Each x element is read exactly once; also writes xb. Deterministic partials.
__global__ __launch_bounds__(256)
void k_route(const float* __restrict__ x, const float* __restrict__ Wsw,
             unsigned short* __restrict__ xb, float* __restrict__ partials) {
    int g = blockIdx.x & 127;
    int s = blockIdx.x >> 7;
    int team = threadIdx.x >> 5;
    int j = threadIdx.x & 31;
    int b = g * 8 + team;
    const float* xr = x + (size_t)b * 15360 + s * 1920;
    unsigned short* xbr = xb + (size_t)b * 15360 + s * 1920;
    float a[8];
#pragma unroll
    for (int e = 0; e < 8; ++e) a[e] = 0.f;
    for (int it = 0; it < 15; ++it) {
        int k = it * 128 + j * 4;
        float4 xv = *(const float4*)(xr + k);
        ushort4 o;
        o.x = f2bf(xv.x); o.y = f2bf(xv.y); o.z = f2bf(xv.z); o.w = f2bf(xv.w);
        *(ushort4*)(xbr + k) = o;
        float xa[4] = {xv.x, xv.y, xv.z, xv.w};
        const float* w = Wsw + (size_t)(s * 1920 + k) * 8;
#pragma unroll
        for (int c = 0; c < 4; ++c) {
            float4 w0 = *(const float4*)(w + c * 8);
            float4 w1 = *(const float4*)(w + c * 8 + 4);
            float xc = xa[c];
            a[0] += xc * w0.x; a[1] += xc * w0.y; a[2] += xc * w0.z; a[3] += xc * w0.w;
            a[4] += xc * w1.x; a[5] += xc * w1.y; a[6] += xc * w1.z; a[7] += xc * w1.w;
        }
    }
#pragma unroll
    for (int m = 16; m >= 1; m >>= 1) {
#pragma unroll
        for (int e = 0; e < 8; ++e) a[e] += __shfl_xor(a[e], m);
    }
    if (j == 0) {
        float4* p = (float4*)(partials + ((size_t)(s * 1024) + b) * 8);
        p[0] = make_float4(a[0], a[1], a[2], a[3]);
        p[1] = make_float4(a[4], a[5], a[6], a[7]);
    }
}

// ---------------- top-CAP per expert by rank + inverse (per-batch) slot lists.
// grid 32 = 8 experts x 4 candidate-quarters. Ties broken by lower index (matches lax.top_k).
__global__ __launch_bounds__(256)
void k_topk(const float* __restrict__ partials, const float* __restrict__ bsw,
            int* __restrict__ idxb, int* __restrict__ cntb, int* __restrict__ slotb) {
    __shared__ float v[NB];
    int e = blockIdx.x >> 2;
    int q = blockIdx.x & 3;
    int tid = threadIdx.x;
    float bs[8];
#pragma unroll
    for (int i = 0; i < 8; ++i) bs[i] = bsw[i];
#pragma unroll
    for (int rr = 0; rr < 4; ++rr) {
        int row = rr * 256 + tid;
        float l[8];
#pragma unroll
        for (int i = 0; i < 8; ++i) l[i] = bs[i];
#pragma unroll
        for (int s = 0; s < 8; ++s) {
            const float4* p = (const float4*)(partials + ((size_t)(s * 1024) + row) * 8);
            float4 p0 = p[0], p1 = p[1];
            l[0] += p0.x; l[1] += p0.y; l[2] += p0.z; l[3] += p0.w;
            l[4] += p1.x; l[5] += p1.y; l[6] += p1.z; l[7] += p1.w;
        }
        float m = l[0];
#pragma unroll
        for (int i = 1; i < 8; ++i) m = fmaxf(m, l[i]);
        float sum = 0.f;
#pragma unroll
        for (int i = 0; i < 8; ++i) sum += expf(l[i] - m);
        v[row] = expf(l[e] - m) / sum;
    }
    __syncthreads();
    int cand = q * 256 + tid;
    float mv = v[cand];
    int cnt = 0;
    for (int jj = 0; jj < NB; ++jj) {
        float vj = v[jj];
        cnt += (vj > mv) || (vj == mv && jj < cand);
    }
    if (cnt < NCAP) {
        idxb[e * NCAP + cnt] = cand;
        int pos = atomicAdd(&cntb[cand], 1);
        slotb[cand * 8 + pos] = e * NCAP + cnt;
    }
}

// ---------------- fused expert MLP: gather -> GEMM1 -> GELU -> GEMM2 -> coalesced oe store
__global__ __launch_bounds__(256, 3)
void k_mlp(const unsigned short* __restrict__ xb,
           const unsigned short* __restrict__ W1b,
           const unsigned short* __restrict__ W2b,
           const float* __restrict__ b1,
           const float* __restrict__ b2,
           const int* __restrict__ idxb,
           unsigned short* __restrict__ oe) {
    __shared__ __align__(16) unsigned short Alds[BM * A_PAD];   // 33792 B
    __shared__ __align__(16) unsigned short Plds[BM * P_PAD];   // 16896 B

    int e  = blockIdx.x & 7;           // XCD swizzle: expert e pinned to XCD e -> 1MB weights L2-resident
    int bm = blockIdx.x >> 3;
    int tb = bm * BM;
    int tid = threadIdx.x;
    int lane = tid & 63, wv = tid >> 6;
    int quad = lane >> 4, l15 = lane & 15;

    // stage A tile [64 x 256] bf16 (gathered token rows)
    {
        int lr = tid >> 2;
        int s4 = tid & 3;
        int t = tb + lr;
        int c = t / 60;
        int s = t - c * 60;
        int bidx = idxb[e * NCAP + c];
        const unsigned short* src = xb + ((size_t)(bidx * 60 + s)) * 256;
#pragma unroll
        for (int j = 0; j < 8; ++j) {
            int seg = j * 4 + s4;
            *(short8*)(&Alds[lr * A_PAD + seg * 8]) = *(const short8*)(src + seg * 8);
        }
    }
    __syncthreads();

    floatx4 acc2[4][4];
#pragma unroll
    for (int mt = 0; mt < 4; ++mt)
#pragma unroll
        for (int nt = 0; nt < 4; ++nt) acc2[mt][nt] = 0.f;

    for (int ch = 0; ch < 8; ++ch) {
        // ---- GEMM1: P[64,128-chunk] ; wave owns cols [wv*32, wv*32+32)
        floatx4 pacc[4][2];
#pragma unroll
        for (int mt = 0; mt < 4; ++mt) { pacc[mt][0] = 0.f; pacc[mt][1] = 0.f; }
#pragma unroll
        for (int kt = 0; kt < 8; ++kt) {
            short8 af[4];
#pragma unroll
            for (int mt = 0; mt < 4; ++mt)
                af[mt] = *(const short8*)(&Alds[(mt * 16 + l15) * A_PAD + kt * 32 + quad * 8]);
#pragma unroll
            for (int nt = 0; nt < 2; ++nt) {
                int hnt = ch * 8 + wv * 2 + nt;
                short8 bf = *(const short8*)(W1b + ((size_t)((e * 64 + hnt) * 8 + kt)) * 512 + lane * 8);
#pragma unroll
                for (int mt = 0; mt < 4; ++mt)
                    pacc[mt][nt] = __builtin_amdgcn_mfma_f32_16x16x32_bf16(af[mt], bf, pacc[mt][nt], 0, 0, 0);
            }
        }
        __syncthreads();   // prev chunk's GEMM2 reads done before overwriting Plds
        // ---- bias + fast GELU (sigmoid form, err ~3e-4) -> Plds
#pragma unroll
        for (int nt = 0; nt < 2; ++nt) {
            int cl = wv * 32 + nt * 16 + l15;
            float bias = b1[e * NH + ch * 128 + cl];
#pragma unroll
            for (int mt = 0; mt < 4; ++mt) {
#pragma unroll
                for (int r = 0; r < 4; ++r) {
                    float vv = pacc[mt][nt][r] + bias;
                    float t2 = vv * vv;
                    float z = vv * fmaf(t2, -0.0713548162726f, -1.5957691216057308f);
                    float g = vv * __builtin_amdgcn_rcpf(1.0f + __expf(z));
                    Plds[(mt * 16 + quad * 4 + r) * P_PAD + cl] = f2bf(g);
                }
            }
        }
        __syncthreads();
        // ---- GEMM2: acc2 += P_chunk @ W2[chunk rows] ; wave owns cols [wv*64, wv*64+64)
#pragma unroll
        for (int kt = 0; kt < 4; ++kt) {
            short8 pf[4];
#pragma unroll
            for (int mt = 0; mt < 4; ++mt) {
                const unsigned short* pb = &Plds[(mt * 16 + l15) * P_PAD + kt * 32 + quad * 8];
                s4v p0 = *(const s4v*)(pb);
                s4v p1 = *(const s4v*)(pb + 4);
                pf[mt] = __builtin_shufflevector(p0, p1, 0, 1, 2, 3, 4, 5, 6, 7);
            }
            int kg = ch * 4 + kt;
#pragma unroll
            for (int nt = 0; nt < 4; ++nt) {
                int dnt = wv * 4 + nt;
                short8 wf = *(const short8*)(W2b + ((size_t)((e * 16 + dnt) * 32 + kg)) * 512 + lane * 8);
#pragma unroll
                for (int mt = 0; mt < 4; ++mt)
                    acc2[mt][nt] = __builtin_amdgcn_mfma_f32_16x16x32_bf16(pf[mt], wf, acc2[mt][nt], 0, 0, 0);
            }
        }
    }

    // ---- epilogue: + b2, bf16 store to oe[e*15360 + t][col]  (no atomics)
    float b2v[4];
#pragma unroll
    for (int nt = 0; nt < 4; ++nt) b2v[nt] = b2[e * ND + wv * 64 + nt * 16 + l15];
#pragma unroll
    for (int mt = 0; mt < 4; ++mt) {
#pragma unroll
        for (int r = 0; r < 4; ++r) {
            int t = tb + mt * 16 + quad * 4 + r;
            unsigned short* dst = oe + ((size_t)(e * NTOK + t)) * 256 + wv * 64 + l15;
#pragma unroll
            for (int nt = 0; nt < 4; ++nt)
                dst[nt * 16] = f2bf(acc2[mt][nt][r] + b2v[nt]);
        }
    }
}

// ---------------- combine (gather per-batch slots) + residual + LayerNorm
__global__ void k_ln(const float* __restrict__ x, const unsigned short* __restrict__ oe,
                     const int* __restrict__ cntb, const int* __restrict__ slotb,
                     const float* __restrict__ gamma, const float* __restrict__ beta,
                     float* __restrict__ out) {
    int row = blockIdx.x * 4 + (threadIdx.x >> 6);
    int lane = threadIdx.x & 63;
    int b = row / 60;
    int s = row - b * 60;
    float4 v = ((const float4*)(x + (size_t)row * 256))[lane];
    int cnt = cntb[b];
    const int* sl = slotb + b * 8;
    for (int i = 0; i < cnt; ++i) {
        int slot = sl[i];
        ushort4 ov = ((const ushort4*)(oe + ((size_t)slot * 60 + s) * 256))[lane];
        v.x += bf2f(ov.x); v.y += bf2f(ov.y); v.z += bf2f(ov.z); v.w += bf2f(ov.w);
    }
    float sm = v.x + v.y + v.z + v.w;
    float q = v.x * v.x + v.y * v.y + v.z * v.z + v.w * v.w;
#pragma unroll
    for (int off = 32; off >= 1; off >>= 1) {
        sm += __shfl_xor(sm, off);
        q  += __shfl_xor(q, off);
    }
    float mu  = sm * (1.0f / 256.0f);
    float var = q * (1.0f / 256.0f) - mu * mu;
    float rs  = rsqrtf(var + 1e-5f);
    float4 g  = ((const float4*)gamma)[lane];
    float4 bt = ((const float4*)beta)[lane];
    float4 o;
    o.x = (v.x - mu) * rs * g.x + bt.x;
    o.y = (v.y - mu) * rs * g.y + bt.y;
    o.z = (v.z - mu) * rs * g.z + bt.z;
    o.w = (v.w - mu) * rs * g.w + bt.w;
    ((float4*)(out + (size_t)row * 256))[lane] = o;
}

extern "C" void kernel_launch(void* const* d_in, const int* in_sizes, int n_in,
                              void* d_out, int out_size, void* d_ws, size_t ws_size,
                              hipStream_t stream) {
    const float* x     = (const float*)d_in[0];
    const float* Wsw   = (const float*)d_in[1];
    const float* bsw   = (const float*)d_in[2];
    const float* W1    = (const float*)d_in[3];
    const float* b1    = (const float*)d_in[4];
    const float* W2    = (const float*)d_in[5];
    const float* b2    = (const float*)d_in[6];
    const float* gamma = (const float*)d_in[7];
    const float* beta  = (const float*)d_in[8];
    float* out = (float*)d_out;

    char* ws = (char*)d_ws;
    size_t off = 0;
    auto alloc = [&](size_t bytes) { void* p = ws + off; off += (bytes + 255) & ~255ull; return p; };
    float*          partials = (float*)alloc((size_t)8 * NB * NE * 4);     // 256 KB
    int*            idxb     = (int*)alloc((size_t)NE * NCAP * 4);
    int*            cntb     = (int*)alloc((size_t)NB * 4);
    int*            slotb    = (int*)alloc((size_t)NB * 8 * 4);
    unsigned short* xb       = (unsigned short*)alloc((size_t)NB * NS * ND * 2);
    unsigned short* W1b      = (unsigned short*)alloc((size_t)NE * ND * NH * 2);
    unsigned short* W2b      = (unsigned short*)alloc((size_t)NE * NH * ND * 2);
    unsigned short* oe       = (unsigned short*)alloc((size_t)NE * NTOK * ND * 2);  // 60 MB
    (void)ws_size; (void)in_sizes; (void)n_in; (void)out_size;

    hipMemsetAsync(cntb, 0, (size_t)NB * 4, stream);
    k_route<<<1024, 256, 0, stream>>>(x, Wsw, xb, partials);
    k_pack_w1<<<2048, 256, 0, stream>>>(W1, W1b);
    k_pack_w2<<<2048, 256, 0, stream>>>(W2, W2b);
    k_topk<<<32, 256, 0, stream>>>(partials, bsw, idxb, cntb, slotb);
    k_mlp<<<NE * NBLK, 256, 0, stream>>>(xb, W1b, W2b, b1, b2, idxb, oe);
    k_ln<<<NB * NS / 4, 256, 0, stream>>>(x, oe, cntb, slotb, gamma, beta, out);
}

// Round 3
// 442.776 us; speedup vs baseline: 1.1492x; 1.1492x over previous
//
#include <hip/hip_runtime.h>
#include <hip/hip_bf16.h>
#include <math.h>

#define NB   1024
#define NS   60
#define ND   256
#define NH   1024
#define NE   8
#define NCAP 256
#define NTOK (NCAP*NS)      // 15360 tokens per expert
#define BM   64
#define NBLK (NTOK/BM)      // 240 row-tiles per expert

typedef __attribute__((ext_vector_type(8)))  short short8;
typedef __attribute__((ext_vector_type(16))) float floatx16;

__device__ __forceinline__ unsigned short f2bf(float f) {
    union { float f; unsigned u; } cv; cv.f = f;
    unsigned u = cv.u;
    u += 0x7FFFu + ((u >> 16) & 1u);
    return (unsigned short)(u >> 16);
}
__device__ __forceinline__ float bf2f(unsigned short h) {
    union { unsigned u; float f; } c; c.u = ((unsigned)h) << 16; return c.f;
}
__device__ __forceinline__ unsigned pk2bf(float a, float b) {
    return (unsigned)f2bf(a) | ((unsigned)f2bf(b) << 16);
}

// ---------------- fused weight pack: W1^T and W2^T into 32x32x16 A-operand fragment order
// W1t frag (e, ht0..31, kt0..15): elem(lane,j) = W1[e][k=kt*16+(lane>>5)*8+j][h=ht*32+(lane&31)]
// W2t frag (e, dt0..7,  kt0..63): elem(lane,j) = W2[e][h=kt*16+(lane>>5)*8+j][d=dt*32+(lane&31)]
__global__ void k_pack(const float* __restrict__ W1, const float* __restrict__ W2,
                       unsigned short* __restrict__ W1t, unsigned short* __restrict__ W2t) {
    int idx = blockIdx.x * 256 + threadIdx.x;
    if (idx < 524288) {                       // W1 part: e x k(256) x h4(256)
        int h4 = idx & 255;
        int k  = (idx >> 8) & 255;
        int e  = idx >> 16;
        float4 w = *(const float4*)(W1 + ((size_t)(e * 256 + k)) * 1024 + h4 * 4);
        float wv[4] = {w.x, w.y, w.z, w.w};
        int lane_k = ((k >> 3) & 1) * 32;
        int kt = k >> 4, j = k & 7;
#pragma unroll
        for (int c = 0; c < 4; ++c) {
            int h = h4 * 4 + c;
            int frag = (e * 32 + (h >> 5)) * 16 + kt;
            W1t[(size_t)frag * 512 + ((h & 31) + lane_k) * 8 + j] = f2bf(wv[c]);
        }
    } else {                                  // W2 part: e x h(1024) x d4(64)
        int i2 = idx - 524288;
        int d4 = i2 & 63;
        int h  = (i2 >> 6) & 1023;
        int e  = i2 >> 16;
        float4 w = *(const float4*)(W2 + ((size_t)(e * 1024 + h)) * 256 + d4 * 4);
        float wv[4] = {w.x, w.y, w.z, w.w};
        int lane_k = ((h >> 3) & 1) * 32;
        int kt = h >> 4, j = h & 7;
#pragma unroll
        for (int c = 0; c < 4; ++c) {
            int d = d4 * 4 + c;
            int frag = (e * 8 + (d >> 5)) * 64 + kt;
            W2t[(size_t)frag * 512 + ((d & 31) + lane_k) * 8 + j] = f2bf(wv[c]);
        }
    }
}

// ---------------- routing split-K GEMM fused with x->bf16 prep
__global__ __launch_bounds__(256)
void k_route(const float* __restrict__ x, const float* __restrict__ Wsw,
             unsigned short* __restrict__ xb, float* __restrict__ partials) {
    int g = blockIdx.x & 127;
    int s = blockIdx.x >> 7;
    int team = threadIdx.x >> 5;
    int j = threadIdx.x & 31;
    int b = g * 8 + team;
    const float* xr = x + (size_t)b * 15360 + s * 1920;
    unsigned short* xbr = xb + (size_t)b * 15360 + s * 1920;
    float a[8];
#pragma unroll
    for (int e = 0; e < 8; ++e) a[e] = 0.f;
    for (int it = 0; it < 15; ++it) {
        int k = it * 128 + j * 4;
        float4 xv = *(const float4*)(xr + k);
        ushort4 o;
        o.x = f2bf(xv.x); o.y = f2bf(xv.y); o.z = f2bf(xv.z); o.w = f2bf(xv.w);
        *(ushort4*)(xbr + k) = o;
        float xa[4] = {xv.x, xv.y, xv.z, xv.w};
        const float* w = Wsw + (size_t)(s * 1920 + k) * 8;
#pragma unroll
        for (int c = 0; c < 4; ++c) {
            float4 w0 = *(const float4*)(w + c * 8);
            float4 w1 = *(const float4*)(w + c * 8 + 4);
            float xc = xa[c];
            a[0] += xc * w0.x; a[1] += xc * w0.y; a[2] += xc * w0.z; a[3] += xc * w0.w;
            a[4] += xc * w1.x; a[5] += xc * w1.y; a[6] += xc * w1.z; a[7] += xc * w1.w;
        }
    }
#pragma unroll
    for (int m = 16; m >= 1; m >>= 1) {
#pragma unroll
        for (int e = 0; e < 8; ++e) a[e] += __shfl_xor(a[e], m);
    }
    if (j == 0) {
        float4* p = (float4*)(partials + ((size_t)(s * 1024) + b) * 8);
        p[0] = make_float4(a[0], a[1], a[2], a[3]);
        p[1] = make_float4(a[4], a[5], a[6], a[7]);
    }
}

// ---------------- top-CAP per expert by rank + inverse slot lists (tie: lower index)
__global__ __launch_bounds__(256)
void k_topk(const float* __restrict__ partials, const float* __restrict__ bsw,
            int* __restrict__ idxb, int* __restrict__ cntb, int* __restrict__ slotb) {
    __shared__ float v[NB];
    int e = blockIdx.x >> 2;
    int q = blockIdx.x & 3;
    int tid = threadIdx.x;
    float bs[8];
#pragma unroll
    for (int i = 0; i < 8; ++i) bs[i] = bsw[i];
#pragma unroll
    for (int rr = 0; rr < 4; ++rr) {
        int row = rr * 256 + tid;
        float l[8];
#pragma unroll
        for (int i = 0; i < 8; ++i) l[i] = bs[i];
#pragma unroll
        for (int s = 0; s < 8; ++s) {
            const float4* p = (const float4*)(partials + ((size_t)(s * 1024) + row) * 8);
            float4 p0 = p[0], p1 = p[1];
            l[0] += p0.x; l[1] += p0.y; l[2] += p0.z; l[3] += p0.w;
            l[4] += p1.x; l[5] += p1.y; l[6] += p1.z; l[7] += p1.w;
        }
        float m = l[0];
#pragma unroll
        for (int i = 1; i < 8; ++i) m = fmaxf(m, l[i]);
        float sum = 0.f;
#pragma unroll
        for (int i = 0; i < 8; ++i) sum += expf(l[i] - m);
        v[row] = expf(l[e] - m) / sum;
    }
    __syncthreads();
    int cand = q * 256 + tid;
    float mv = v[cand];
    int cnt = 0;
    for (int jj = 0; jj < NB; ++jj) {
        float vj = v[jj];
        cnt += (vj > mv) || (vj == mv && jj < cand);
    }
    if (cnt < NCAP) {
        idxb[e * NCAP + cnt] = cand;
        int pos = atomicAdd(&cntb[cand], 1);
        slotb[cand * 8 + pos] = e * NCAP + cnt;
    }
}

// ---------------- fused expert MLP, 32x32x16 MFMA, XOR-swizzled LDS, no padding.
// GEMM1: P^T[h][m] = W1^T(A) x X(B);  GEMM2: O^T[d][m] = W2^T(A) x P(B).
__global__ __launch_bounds__(256, 2)
void k_mlp(const unsigned short* __restrict__ xb,
           const unsigned short* __restrict__ W1t,
           const unsigned short* __restrict__ W2t,
           const float* __restrict__ b1,
           const float* __restrict__ b2,
           const int* __restrict__ idxb,
           unsigned short* __restrict__ oe) {
    __shared__ __align__(16) unsigned short Alds[BM * 256];   // 32768 B, unit(16B)-swizzled
    __shared__ __align__(16) unsigned short Plds[BM * 256];   // 32768 B, unit-swizzled

    int e  = blockIdx.x / NBLK;     // rolling expert mapping (r1-style: ~2 experts resident)
    int bm = blockIdx.x % NBLK;
    int tb = bm * BM;
    int tid = threadIdx.x;
    int lane = tid & 63, w = tid >> 6;
    int m31 = lane & 31, hi = lane >> 5;

    // stage gathered X tile [64 tokens x 256 d], bf16, unit-swizzled
    {
        int lr = tid >> 2;          // token row 0..63
        int s4 = tid & 3;
        int t = tb + lr;
        int c = t / 60;
        int s = t - c * 60;
        int bidx = idxb[e * NCAP + c];
        const unsigned short* src = xb + ((size_t)(bidx * 60 + s)) * 256;
#pragma unroll
        for (int jj = 0; jj < 8; ++jj) {
            int u = jj * 4 + s4;
            int up = u ^ (lr & 15);
            *(short8*)(&Alds[lr * 256 + up * 8]) = *(const short8*)(src + u * 8);
        }
    }
    __syncthreads();

    floatx16 acc2[2][2];
#pragma unroll
    for (int mt = 0; mt < 2; ++mt)
#pragma unroll
        for (int nt = 0; nt < 2; ++nt) acc2[mt][nt] = 0.f;

    for (int ch = 0; ch < 4; ++ch) {
        // ---- GEMM1: wave w computes P^T rows h = ch*256 + w*64 + mt*32, all 64 tokens
        floatx16 pacc[2][2];
#pragma unroll
        for (int mt = 0; mt < 2; ++mt) { pacc[mt][0] = 0.f; pacc[mt][1] = 0.f; }
#pragma unroll 4
        for (int kt = 0; kt < 16; ++kt) {
            short8 bx[2];
#pragma unroll
            for (int nt = 0; nt < 2; ++nt) {
                int row = nt * 32 + m31;
                int up = (kt * 2 + hi) ^ (row & 15);
                bx[nt] = *(const short8*)(&Alds[row * 256 + up * 8]);
            }
#pragma unroll
            for (int mt = 0; mt < 2; ++mt) {
                int ht = ch * 8 + w * 2 + mt;
                short8 aw = *(const short8*)(W1t + ((size_t)((e * 32 + ht) * 16 + kt)) * 512 + lane * 8);
#pragma unroll
                for (int nt = 0; nt < 2; ++nt)
                    pacc[mt][nt] = __builtin_amdgcn_mfma_f32_32x32x16_bf16(aw, bx[nt], pacc[mt][nt], 0, 0, 0);
            }
        }
        __syncthreads();   // prev chunk's GEMM2 done reading Plds
        // ---- bias + fast GELU -> Plds (b64 writes, reg-quads = 4 consecutive h)
#pragma unroll
        for (int mt = 0; mt < 2; ++mt) {
#pragma unroll
            for (int q = 0; q < 4; ++q) {
                int hh = w * 64 + mt * 32 + 8 * q + 4 * hi;        // h within chunk
                float4 bb = *(const float4*)(b1 + e * NH + ch * 256 + hh);
                float bv[4] = {bb.x, bb.y, bb.z, bb.w};
#pragma unroll
                for (int nt = 0; nt < 2; ++nt) {
                    float g[4];
#pragma unroll
                    for (int r = 0; r < 4; ++r) {
                        float vv = pacc[mt][nt][4 * q + r] + bv[r];
                        float t2 = vv * vv;
                        float z = vv * fmaf(t2, -0.0713548162726f, -1.5957691216057308f);
                        g[r] = vv * __builtin_amdgcn_rcpf(1.0f + __expf(z));
                    }
                    int row = nt * 32 + m31;
                    int up = (hh >> 3) ^ (row & 15);
                    uint2 pk = {pk2bf(g[0], g[1]), pk2bf(g[2], g[3])};
                    *(uint2*)(&Plds[row * 256 + up * 8 + 4 * hi]) = pk;
                }
            }
        }
        __syncthreads();
        // ---- GEMM2: wave w accumulates O^T rows d = w*64 + mt*32 over this chunk's h
#pragma unroll 4
        for (int kt = 0; kt < 16; ++kt) {
            short8 bp[2];
#pragma unroll
            for (int nt = 0; nt < 2; ++nt) {
                int row = nt * 32 + m31;
                int up = (kt * 2 + hi) ^ (row & 15);
                bp[nt] = *(const short8*)(&Plds[row * 256 + up * 8]);
            }
            int ktg = ch * 16 + kt;
#pragma unroll
            for (int mt = 0; mt < 2; ++mt) {
                int dt = w * 2 + mt;
                short8 aw = *(const short8*)(W2t + ((size_t)((e * 8 + dt) * 64 + ktg)) * 512 + lane * 8);
#pragma unroll
                for (int nt = 0; nt < 2; ++nt)
                    acc2[mt][nt] = __builtin_amdgcn_mfma_f32_32x32x16_bf16(aw, bp[nt], acc2[mt][nt], 0, 0, 0);
            }
        }
    }

    // ---- epilogue: +b2, bf16, stage O in Plds (swizzled), then coalesced 16B stores
    __syncthreads();
#pragma unroll
    for (int mt = 0; mt < 2; ++mt) {
#pragma unroll
        for (int q = 0; q < 4; ++q) {
            int dd = w * 64 + mt * 32 + 8 * q + 4 * hi;
            float4 bb = *(const float4*)(b2 + e * ND + dd);
            float bv[4] = {bb.x, bb.y, bb.z, bb.w};
#pragma unroll
            for (int nt = 0; nt < 2; ++nt) {
                int row = nt * 32 + m31;
                int up = (dd >> 3) ^ (row & 15);
                uint2 pk = {pk2bf(acc2[mt][nt][4 * q + 0] + bv[0], acc2[mt][nt][4 * q + 1] + bv[1]),
                            pk2bf(acc2[mt][nt][4 * q + 2] + bv[2], acc2[mt][nt][4 * q + 3] + bv[3])};
                *(uint2*)(&Plds[row * 256 + up * 8 + 4 * hi]) = pk;
            }
        }
    }
    __syncthreads();
    {
        int row = tid >> 2;
        int c = tid & 3;
        unsigned short* dst = oe + ((size_t)(e * NTOK + tb + row)) * 256;
#pragma unroll
        for (int uu = 0; uu < 8; ++uu) {
            int u = c + uu * 4;
            int up = u ^ (row & 15);
            *(short8*)(dst + u * 8) = *(const short8*)(&Plds[row * 256 + up * 8]);
        }
    }
}

// ---------------- combine (gather per-batch slots) + residual + LayerNorm
__global__ void k_ln(const float* __restrict__ x, const unsigned short* __restrict__ oe,
                     const int* __restrict__ cntb, const int* __restrict__ slotb,
                     const float* __restrict__ gamma, const float* __restrict__ beta,
                     float* __restrict__ out) {
    int row = blockIdx.x * 4 + (threadIdx.x >> 6);
    int lane = threadIdx.x & 63;
    int b = row / 60;
    int s = row - b * 60;
    float4 v = ((const float4*)(x + (size_t)row * 256))[lane];
    int cnt = cntb[b];
    const int* sl = slotb + b * 8;
    for (int i = 0; i < cnt; ++i) {
        int slot = sl[i];
        ushort4 ov = ((const ushort4*)(oe + ((size_t)slot * 60 + s) * 256))[lane];
        v.x += bf2f(ov.x); v.y += bf2f(ov.y); v.z += bf2f(ov.z); v.w += bf2f(ov.w);
    }
    float sm = v.x + v.y + v.z + v.w;
    float q = v.x * v.x + v.y * v.y + v.z * v.z + v.w * v.w;
#pragma unroll
    for (int off = 32; off >= 1; off >>= 1) {
        sm += __shfl_xor(sm, off);
        q  += __shfl_xor(q, off);
    }
    float mu  = sm * (1.0f / 256.0f);
    float var = q * (1.0f / 256.0f) - mu * mu;
    float rs  = rsqrtf(var + 1e-5f);
    float4 g  = ((const float4*)gamma)[lane];
    float4 bt = ((const float4*)beta)[lane];
    float4 o;
    o.x = (v.x - mu) * rs * g.x + bt.x;
    o.y = (v.y - mu) * rs * g.y + bt.y;
    o.z = (v.z - mu) * rs * g.z + bt.z;
    o.w = (v.w - mu) * rs * g.w + bt.w;
    ((float4*)(out + (size_t)row * 256))[lane] = o;
}

extern "C" void kernel_launch(void* const* d_in, const int* in_sizes, int n_in,
                              void* d_out, int out_size, void* d_ws, size_t ws_size,
                              hipStream_t stream) {
    const float* x     = (const float*)d_in[0];
    const float* Wsw   = (const float*)d_in[1];
    const float* bsw   = (const float*)d_in[2];
    const float* W1    = (const float*)d_in[3];
    const float* b1    = (const float*)d_in[4];
    const float* W2    = (const float*)d_in[5];
    const float* b2    = (const float*)d_in[6];
    const float* gamma = (const float*)d_in[7];
    const float* beta  = (const float*)d_in[8];
    float* out = (float*)d_out;

    char* ws = (char*)d_ws;
    size_t off = 0;
    auto alloc = [&](size_t bytes) { void* p = ws + off; off += (bytes + 255) & ~255ull; return p; };
    float*          partials = (float*)alloc((size_t)8 * NB * NE * 4);
    int*            idxb     = (int*)alloc((size_t)NE * NCAP * 4);
    int*            cntb     = (int*)alloc((size_t)NB * 4);
    int*            slotb    = (int*)alloc((size_t)NB * 8 * 4);
    unsigned short* xb       = (unsigned short*)alloc((size_t)NB * NS * ND * 2);
    unsigned short* W1t      = (unsigned short*)alloc((size_t)NE * ND * NH * 2);
    unsigned short* W2t      = (unsigned short*)alloc((size_t)NE * NH * ND * 2);
    unsigned short* oe       = (unsigned short*)alloc((size_t)NE * NTOK * ND * 2);
    (void)ws_size; (void)in_sizes; (void)n_in; (void)out_size;

    hipMemsetAsync(cntb, 0, (size_t)NB * 4, stream);
    k_route<<<1024, 256, 0, stream>>>(x, Wsw, xb, partials);
    k_pack<<<4096, 256, 0, stream>>>(W1, W2, W1t, W2t);
    k_topk<<<32, 256, 0, stream>>>(partials, bsw, idxb, cntb, slotb);
    k_mlp<<<NE * NBLK, 256, 0, stream>>>(xb, W1t, W2t, b1, b2, idxb, oe);
    k_ln<<<NB * NS / 4, 256, 0, stream>>>(x, oe, cntb, slotb, gamma, beta, out);
}

// Round 4
// 395.105 us; speedup vs baseline: 1.2879x; 1.1207x over previous
//
#include <hip/hip_runtime.h>
#include <hip/hip_bf16.h>
#include <math.h>

#define NB   1024
#define NS   60
#define ND   256
#define NH   1024
#define NE   8
#define NCAP 256
#define NTOK (NCAP*NS)      // 15360 tokens per expert
#define BM   64
#define NBLK (NTOK/BM)      // 240 row-tiles per expert

typedef __attribute__((ext_vector_type(8)))  short short8;
typedef __attribute__((ext_vector_type(16))) float floatx16;

__device__ __forceinline__ unsigned short f2bf(float f) {
    union { float f; unsigned u; } cv; cv.f = f;
    unsigned u = cv.u;
    u += 0x7FFFu + ((u >> 16) & 1u);
    return (unsigned short)(u >> 16);
}
__device__ __forceinline__ float bf2f(unsigned short h) {
    union { unsigned u; float f; } c; c.u = ((unsigned)h) << 16; return c.f;
}
// packed f32x2 -> bf16x2 (hardware cvt on gfx950; manual RNE fallback)
__device__ __forceinline__ unsigned cvt_pk_bf16(float a, float b) {
#if defined(__has_builtin) && __has_builtin(__builtin_amdgcn_cvt_pk_bf16_f32)
    typedef __attribute__((ext_vector_type(2))) __bf16 bf16x2;
    union { bf16x2 v; unsigned u; } cc;
    cc.v = __builtin_amdgcn_cvt_pk_bf16_f32(a, b);
    return cc.u;
#else
    return (unsigned)f2bf(a) | ((unsigned)f2bf(b) << 16);
#endif
}

// GELU: 0.5*x*(1+erf(x/sqrt2)); erf(t/sqrt2) ~ t*2*P(t^2), clamp |t|<=3.25.
// P = halved interp coeffs at u = t^2 in {0,1,4,9,10.5625}; |erf err| <3e-4 for |t|<1.6.
#define GELU_H0  0.39894228f
#define GELU_H1 -0.065680755f
#define GELU_H2  0.008727065f
#define GELU_H3 -0.000664585f
#define GELU_H4  2.07274e-5f
__device__ __forceinline__ float fast_gelu(float xx) {
    float t = __builtin_amdgcn_fmed3f(xx, -3.25f, 3.25f);
    float s = t * t;
    float p = fmaf(s, GELU_H4, GELU_H3);
    p = fmaf(s, p, GELU_H2);
    p = fmaf(s, p, GELU_H1);
    p = fmaf(s, p, GELU_H0);
    return xx * fmaf(t, p, 0.5f);
}

// ---------------- pack W1^T / W2^T into 32x32x16 A-operand fragment order.
// Coalesced: each thread emits 16 contiguous bytes of one fragment.
// W1t frag (e,ht,kt): elem(lane,j) = W1[e][kt*16+(lane>>5)*8+j][ht*32+(lane&31)]
// W2t frag (e,dt,kt): elem(lane,j) = W2[e][kt*16+(lane>>5)*8+j][dt*32+(lane&31)]
__global__ __launch_bounds__(256)
void k_pack(const float* __restrict__ W1, const float* __restrict__ W2,
            unsigned short* __restrict__ W1t, unsigned short* __restrict__ W2t) {
    int idx = blockIdx.x * 256 + threadIdx.x;     // 524288
    int lane = idx & 63;
    int m31 = lane & 31, hi = lane >> 5;
    const float* src;
    unsigned short* dst;
    int ldk;
    if (idx < 262144) {            // W1: fi = (e*32+ht)*16+kt
        int fi = idx >> 6;
        int kt = fi & 15;
        int ht = (fi >> 4) & 31;
        int e  = fi >> 9;
        int k0 = kt * 16 + hi * 8;
        int h  = ht * 32 + m31;
        src = W1 + ((size_t)(e * 256 + k0)) * 1024 + h;
        dst = W1t + (size_t)fi * 512 + lane * 8;
        ldk = 1024;
    } else {                       // W2: fi = (e*8+dt)*64+kt
        int i2 = idx - 262144;
        int fi = i2 >> 6;
        int kt = fi & 63;
        int dt = (fi >> 6) & 7;
        int e  = fi >> 9;
        int k0 = kt * 16 + hi * 8;
        int d  = dt * 32 + m31;
        src = W2 + ((size_t)(e * 1024 + k0)) * 256 + d;
        dst = W2t + (size_t)fi * 512 + lane * 8;
        ldk = 256;
    }
    float v[8];
#pragma unroll
    for (int j = 0; j < 8; ++j) v[j] = src[(size_t)j * ldk];
    uint4 o;
    o.x = cvt_pk_bf16(v[0], v[1]);
    o.y = cvt_pk_bf16(v[2], v[3]);
    o.z = cvt_pk_bf16(v[4], v[5]);
    o.w = cvt_pk_bf16(v[6], v[7]);
    *(uint4*)dst = o;
}

// ---------------- routing split-K GEMM fused with x->bf16 prep (+cntb zeroing)
__global__ __launch_bounds__(256)
void k_route(const float* __restrict__ x, const float* __restrict__ Wsw,
             unsigned short* __restrict__ xb, float* __restrict__ partials,
             int* __restrict__ cntb) {
    if (blockIdx.x < 4) cntb[blockIdx.x * 256 + threadIdx.x] = 0;
    int g = blockIdx.x & 127;
    int s = blockIdx.x >> 7;
    int team = threadIdx.x >> 5;
    int j = threadIdx.x & 31;
    int b = g * 8 + team;
    const float* xr = x + (size_t)b * 15360 + s * 1920;
    unsigned short* xbr = xb + (size_t)b * 15360 + s * 1920;
    float a[8];
#pragma unroll
    for (int e = 0; e < 8; ++e) a[e] = 0.f;
    for (int it = 0; it < 15; ++it) {
        int k = it * 128 + j * 4;
        float4 xv = *(const float4*)(xr + k);
        uint2 pk = {cvt_pk_bf16(xv.x, xv.y), cvt_pk_bf16(xv.z, xv.w)};
        *(uint2*)(xbr + k) = pk;
        float xa[4] = {xv.x, xv.y, xv.z, xv.w};
        const float* w = Wsw + (size_t)(s * 1920 + k) * 8;
#pragma unroll
        for (int c = 0; c < 4; ++c) {
            float4 w0 = *(const float4*)(w + c * 8);
            float4 w1 = *(const float4*)(w + c * 8 + 4);
            float xc = xa[c];
            a[0] += xc * w0.x; a[1] += xc * w0.y; a[2] += xc * w0.z; a[3] += xc * w0.w;
            a[4] += xc * w1.x; a[5] += xc * w1.y; a[6] += xc * w1.z; a[7] += xc * w1.w;
        }
    }
#pragma unroll
    for (int m = 16; m >= 1; m >>= 1) {
#pragma unroll
        for (int e = 0; e < 8; ++e) a[e] += __shfl_xor(a[e], m);
    }
    if (j == 0) {
        float4* p = (float4*)(partials + ((size_t)(s * 1024) + b) * 8);
        p[0] = make_float4(a[0], a[1], a[2], a[3]);
        p[1] = make_float4(a[4], a[5], a[6], a[7]);
    }
}

// ---------------- top-CAP per expert by rank + inverse slot lists (tie: lower index)
__global__ __launch_bounds__(256)
void k_topk(const float* __restrict__ partials, const float* __restrict__ bsw,
            int* __restrict__ idxb, int* __restrict__ cntb, int* __restrict__ slotb) {
    __shared__ float v[NB];
    int e = blockIdx.x >> 2;
    int q = blockIdx.x & 3;
    int tid = threadIdx.x;
    float bs[8];
#pragma unroll
    for (int i = 0; i < 8; ++i) bs[i] = bsw[i];
#pragma unroll
    for (int rr = 0; rr < 4; ++rr) {
        int row = rr * 256 + tid;
        float l[8];
#pragma unroll
        for (int i = 0; i < 8; ++i) l[i] = bs[i];
#pragma unroll
        for (int s = 0; s < 8; ++s) {
            const float4* p = (const float4*)(partials + ((size_t)(s * 1024) + row) * 8);
            float4 p0 = p[0], p1 = p[1];
            l[0] += p0.x; l[1] += p0.y; l[2] += p0.z; l[3] += p0.w;
            l[4] += p1.x; l[5] += p1.y; l[6] += p1.z; l[7] += p1.w;
        }
        float m = l[0];
#pragma unroll
        for (int i = 1; i < 8; ++i) m = fmaxf(m, l[i]);
        float sum = 0.f;
#pragma unroll
        for (int i = 0; i < 8; ++i) sum += expf(l[i] - m);
        v[row] = expf(l[e] - m) / sum;
    }
    __syncthreads();
    int cand = q * 256 + tid;
    float mv = v[cand];
    int cnt = 0;
    for (int jj = 0; jj < NB; ++jj) {
        float vj = v[jj];
        cnt += (vj > mv) || (vj == mv && jj < cand);
    }
    if (cnt < NCAP) {
        idxb[e * NCAP + cnt] = cand;
        int pos = atomicAdd(&cntb[cand], 1);
        slotb[cand * 8 + pos] = e * NCAP + cnt;
    }
}

// ---------------- fused expert MLP; fragment-native LDS, chunk=128, 3 blocks/CU
__global__ __launch_bounds__(256, 3)
void k_mlp(const unsigned short* __restrict__ xb,
           const unsigned short* __restrict__ W1t,
           const unsigned short* __restrict__ W2t,
           const float* __restrict__ b1,
           const float* __restrict__ b2,
           const int* __restrict__ idxb,
           unsigned short* __restrict__ oe) {
    __shared__ __align__(16) unsigned short Xf[16384];  // 32 KB, B-frag: ((nt*16+kt)*64+lane)*8
    __shared__ __align__(16) unsigned short Pf[8192];   // 16 KB, B-frag: ((nt*8+kt)*64+lane)*8

    int e  = blockIdx.x / NBLK;
    int bm = blockIdx.x % NBLK;
    int tb = bm * BM;
    int tid = threadIdx.x;
    int lane = tid & 63, w = tid >> 6;
    int m31 = lane & 31, hi = lane >> 5;
    const short8* xfrag = (const short8*)Xf;
    const short8* pfrag = (const short8*)Pf;

    // stage gathered X tile straight into B-operand fragment layout
    {
        int lr = tid >> 2;          // token 0..63
        int s4 = tid & 3;
        int t = tb + lr;
        int c = t / 60;
        int s = t - c * 60;
        int bidx = idxb[e * NCAP + c];
        const unsigned short* src = xb + ((size_t)(bidx * 60 + s)) * 256;
        int nt = lr >> 5, mm = lr & 31;
#pragma unroll
        for (int jj = 0; jj < 8; ++jj) {
            int u = jj * 4 + s4;                 // d-range u*8..u*8+7
            int kt = u >> 1, uh = u & 1;
            *(short8*)(&Xf[(((nt * 16 + kt) * 64) + uh * 32 + mm) * 8]) =
                *(const short8*)(src + u * 8);
        }
    }
    __syncthreads();

    floatx16 acc2[2][2];
#pragma unroll
    for (int mt = 0; mt < 2; ++mt)
#pragma unroll
        for (int nt = 0; nt < 2; ++nt) acc2[mt][nt] = 0.f;

    for (int ch = 0; ch < 8; ++ch) {
        // ---- GEMM1: wave w computes P^T rows h = ch*128 + w*32 .. +32 (all 64 tokens)
        floatx16 pacc[2];
        pacc[0] = 0.f; pacc[1] = 0.f;
        int ht = ch * 4 + w;
        const unsigned short* w1p = W1t + ((size_t)(e * 32 + ht) * 16) * 512 + lane * 8;
#pragma unroll 4
        for (int kt = 0; kt < 16; ++kt) {
            short8 aw = *(const short8*)(w1p + (size_t)kt * 512);
            short8 bx0 = xfrag[kt * 64 + lane];
            short8 bx1 = xfrag[(16 + kt) * 64 + lane];
            pacc[0] = __builtin_amdgcn_mfma_f32_32x32x16_bf16(aw, bx0, pacc[0], 0, 0, 0);
            pacc[1] = __builtin_amdgcn_mfma_f32_32x32x16_bf16(aw, bx1, pacc[1], 0, 0, 0);
        }
        __syncthreads();   // prev chunk's GEMM2 finished reading Pf
        // ---- bias + GELU -> Pf (B-frag layout, imm-offset b64 writes)
        const float* b1c = b1 + e * NH + ch * 128 + w * 32;
#pragma unroll
        for (int q = 0; q < 4; ++q) {
            float4 bb = *(const float4*)(b1c + 8 * q + 4 * hi);
            float bv[4] = {bb.x, bb.y, bb.z, bb.w};
            int ktp = w * 2 + (q >> 1);
#pragma unroll
            for (int nt = 0; nt < 2; ++nt) {
                float g[4];
#pragma unroll
                for (int r = 0; r < 4; ++r)
                    g[r] = fast_gelu(pacc[nt][4 * q + r] + bv[r]);
                uint2 pk = {cvt_pk_bf16(g[0], g[1]), cvt_pk_bf16(g[2], g[3])};
                *(uint2*)(&Pf[(((nt * 8 + ktp) * 64) + (q & 1) * 32 + m31) * 8 + 4 * hi]) = pk;
            }
        }
        __syncthreads();
        // ---- GEMM2: wave w accumulates O^T rows d = w*64..w*64+64 over chunk h
#pragma unroll 4
        for (int kt = 0; kt < 8; ++kt) {
            short8 bp0 = pfrag[kt * 64 + lane];
            short8 bp1 = pfrag[(8 + kt) * 64 + lane];
#pragma unroll
            for (int mt = 0; mt < 2; ++mt) {
                short8 aw = *(const short8*)(W2t +
                    ((size_t)((e * 8 + w * 2 + mt) * 64 + ch * 8 + kt)) * 512 + lane * 8);
                acc2[mt][0] = __builtin_amdgcn_mfma_f32_32x32x16_bf16(aw, bp0, acc2[mt][0], 0, 0, 0);
                acc2[mt][1] = __builtin_amdgcn_mfma_f32_32x32x16_bf16(aw, bp1, acc2[mt][1], 0, 0, 0);
            }
        }
    }

    // ---- epilogue: +b2, bf16, stage O in Xf (16B-unit XOR swizzle), coalesced stores
    // (safe: all Xf reads finished before ch=7's mid-loop barrier)
#pragma unroll
    for (int mt = 0; mt < 2; ++mt) {
#pragma unroll
        for (int q = 0; q < 4; ++q) {
            int dd = w * 64 + mt * 32 + 8 * q + 4 * hi;
            float4 bb = *(const float4*)(b2 + e * ND + dd);
            float bv[4] = {bb.x, bb.y, bb.z, bb.w};
            int u16 = dd >> 3;                 // = 8w+4mt+q
#pragma unroll
            for (int nt = 0; nt < 2; ++nt) {
                int row = nt * 32 + m31;
                int up = u16 ^ (row & 15);
                uint2 pk = {cvt_pk_bf16(acc2[mt][nt][4 * q + 0] + bv[0],
                                        acc2[mt][nt][4 * q + 1] + bv[1]),
                            cvt_pk_bf16(acc2[mt][nt][4 * q + 2] + bv[2],
                                        acc2[mt][nt][4 * q + 3] + bv[3])};
                *(uint2*)(&Xf[row * 256 + up * 8 + 4 * hi]) = pk;
            }
        }
    }
    __syncthreads();
    {
        int row = tid >> 2;
        int c = tid & 3;
        unsigned short* dst = oe + ((size_t)(e * NTOK + tb + row)) * 256;
#pragma unroll
        for (int uu = 0; uu < 8; ++uu) {
            int u = c + uu * 4;
            int up = u ^ (row & 15);
            *(short8*)(dst + u * 8) = *(const short8*)(&Xf[row * 256 + up * 8]);
        }
    }
}

// ---------------- combine (gather per-batch slots) + residual + LayerNorm
__global__ void k_ln(const float* __restrict__ x, const unsigned short* __restrict__ oe,
                     const int* __restrict__ cntb, const int* __restrict__ slotb,
                     const float* __restrict__ gamma, const float* __restrict__ beta,
                     float* __restrict__ out) {
    int row = blockIdx.x * 4 + (threadIdx.x >> 6);
    int lane = threadIdx.x & 63;
    int b = row / 60;
    int s = row - b * 60;
    float4 v = ((const float4*)(x + (size_t)row * 256))[lane];
    int cnt = cntb[b];
    const int* sl = slotb + b * 8;
    for (int i = 0; i < cnt; ++i) {
        int slot = sl[i];
        ushort4 ov = ((const ushort4*)(oe + ((size_t)slot * 60 + s) * 256))[lane];
        v.x += bf2f(ov.x); v.y += bf2f(ov.y); v.z += bf2f(ov.z); v.w += bf2f(ov.w);
    }
    float sm = v.x + v.y + v.z + v.w;
    float q = v.x * v.x + v.y * v.y + v.z * v.z + v.w * v.w;
#pragma unroll
    for (int off = 32; off >= 1; off >>= 1) {
        sm += __shfl_xor(sm, off);
        q  += __shfl_xor(q, off);
    }
    float mu  = sm * (1.0f / 256.0f);
    float var = q * (1.0f / 256.0f) - mu * mu;
    float rs  = rsqrtf(var + 1e-5f);
    float4 g  = ((const float4*)gamma)[lane];
    float4 bt = ((const float4*)beta)[lane];
    float4 o;
    o.x = (v.x - mu) * rs * g.x + bt.x;
    o.y = (v.y - mu) * rs * g.y + bt.y;
    o.z = (v.z - mu) * rs * g.z + bt.z;
    o.w = (v.w - mu) * rs * g.w + bt.w;
    ((float4*)(out + (size_t)row * 256))[lane] = o;
}

extern "C" void kernel_launch(void* const* d_in, const int* in_sizes, int n_in,
                              void* d_out, int out_size, void* d_ws, size_t ws_size,
                              hipStream_t stream) {
    const float* x     = (const float*)d_in[0];
    const float* Wsw   = (const float*)d_in[1];
    const float* bsw   = (const float*)d_in[2];
    const float* W1    = (const float*)d_in[3];
    const float* b1    = (const float*)d_in[4];
    const float* W2    = (const float*)d_in[5];
    const float* b2    = (const float*)d_in[6];
    const float* gamma = (const float*)d_in[7];
    const float* beta  = (const float*)d_in[8];
    float* out = (float*)d_out;

    char* ws = (char*)d_ws;
    size_t off = 0;
    auto alloc = [&](size_t bytes) { void* p = ws + off; off += (bytes + 255) & ~255ull; return p; };
    float*          partials = (float*)alloc((size_t)8 * NB * NE * 4);
    int*            idxb     = (int*)alloc((size_t)NE * NCAP * 4);
    int*            cntb     = (int*)alloc((size_t)NB * 4);
    int*            slotb    = (int*)alloc((size_t)NB * 8 * 4);
    unsigned short* xb       = (unsigned short*)alloc((size_t)NB * NS * ND * 2);
    unsigned short* W1t      = (unsigned short*)alloc((size_t)NE * ND * NH * 2);
    unsigned short* W2t      = (unsigned short*)alloc((size_t)NE * NH * ND * 2);
    unsigned short* oe       = (unsigned short*)alloc((size_t)NE * NTOK * ND * 2);
    (void)ws_size; (void)in_sizes; (void)n_in; (void)out_size;

    k_route<<<1024, 256, 0, stream>>>(x, Wsw, xb, partials, cntb);
    k_pack<<<2048, 256, 0, stream>>>(W1, W2, W1t, W2t);
    k_topk<<<32, 256, 0, stream>>>(partials, bsw, idxb, cntb, slotb);
    k_mlp<<<NE * NBLK, 256, 0, stream>>>(xb, W1t, W2t, b1, b2, idxb, oe);
    k_ln<<<NB * NS / 4, 256, 0, stream>>>(x, oe, cntb, slotb, gamma, beta, out);
}